// Round 11
// baseline (1406.624 us; speedup 1.0000x reference)
//
#include <hip/hip_runtime.h>

// ---------------------------------------------------------------------------
// Sparse MS-Deformable Attention, f32 (+f16 projected value maps).
// Round 11: ALGORITHMIC traffic cut. Rounds 3-10 proved the raw-row gather is
// pinned at ~490 us (8.6 GB L1-side @ ~17 TB/s) against every uarch lever.
// New path: precompute vp = v @ W_val + b_val (f16, [pix][H][32]) with an
// MFMA f16 GEMM (91 GFLOP, HBM-bound ~170-220 us), then gather only 64 B per
// (head,corner): 16x less gather traffic. Coordinates/attn stay f32.
// Falls back to the round-10 path if ws_size < ~381 MB.
// ---------------------------------------------------------------------------

typedef float f32x4 __attribute__((ext_vector_type(4)));
typedef _Float16 f16;
typedef f16 f16x8 __attribute__((ext_vector_type(8)));
typedef f16 f16x4 __attribute__((ext_vector_type(4)));

// Y[n, 0:M] = X[n, 0:256] @ W[256, M] + bias ; 32 rows/block, M threads,
// thread tile = 8 queries x 4 cols. Safe in-place (Y==X).
template<int M>
__global__ __launch_bounds__(M)
void gemm_rb(const float* __restrict__ X, const float* __restrict__ W,
             const float* __restrict__ bias, float* __restrict__ Y) {
    __shared__ float xt[32 * 256];
    const int tid = threadIdx.x;
    const long row0 = (long)blockIdx.x * 32;
    const float4* src = (const float4*)(X + row0 * 256);
    float4* dst4 = (float4*)xt;
    for (int i = tid; i < 32 * 64; i += M) dst4[i] = src[i];
    __syncthreads();

    constexpr int CG = M / 4;
    const int cg = tid % CG, qg = tid / CG;
    const int c0 = cg * 4, q0 = qg * 8;

    f32x4 acc[8];
#pragma unroll
    for (int qi = 0; qi < 8; ++qi) acc[qi] = (f32x4){0.f, 0.f, 0.f, 0.f};

    for (int k4 = 0; k4 < 64; ++k4) {
        f32x4 w[4];
#pragma unroll
        for (int r = 0; r < 4; ++r)
            w[r] = *(const f32x4*)&W[(size_t)(k4 * 4 + r) * M + c0];
        f32x4 xv[8];
#pragma unroll
        for (int qi = 0; qi < 8; ++qi)
            xv[qi] = *(const f32x4*)&xt[(q0 + qi) * 256 + k4 * 4];
#pragma unroll
        for (int qi = 0; qi < 8; ++qi) {
            f32x4 a = acc[qi];
            const f32x4 x = xv[qi];
            a.x = fmaf(x.x, w[0].x, a.x); a.y = fmaf(x.x, w[0].y, a.y);
            a.z = fmaf(x.x, w[0].z, a.z); a.w = fmaf(x.x, w[0].w, a.w);
            a.x = fmaf(x.y, w[1].x, a.x); a.y = fmaf(x.y, w[1].y, a.y);
            a.z = fmaf(x.y, w[1].z, a.z); a.w = fmaf(x.y, w[1].w, a.w);
            a.x = fmaf(x.z, w[2].x, a.x); a.y = fmaf(x.z, w[2].y, a.y);
            a.z = fmaf(x.z, w[2].z, a.z); a.w = fmaf(x.z, w[2].w, a.w);
            a.x = fmaf(x.w, w[3].x, a.x); a.y = fmaf(x.w, w[3].y, a.y);
            a.z = fmaf(x.w, w[3].z, a.z); a.w = fmaf(x.w, w[3].w, a.w);
            acc[qi] = a;
        }
    }

    const f32x4 bv = *(const f32x4*)&bias[c0];
#pragma unroll
    for (int qi = 0; qi < 8; ++qi) {
        f32x4 o = acc[qi];
        o.x += bv.x; o.y += bv.y; o.z += bv.z; o.w += bv.w;
        *(f32x4*)&Y[(size_t)(row0 + q0 + qi) * M + c0] = o;
    }
}

// ---- spatial binning: 64x64 bins of 8x8 px over the 512x512 base frame ----
#define NBINS 4096

__device__ __forceinline__ int bin_of(float ri, float rj) {
    int bi = (int)ri >> 3, bj = (int)rj >> 3;
    bi = min(63, max(0, bi)); bj = min(63, max(0, bj));
    return bi * 64 + bj;
}

__global__ void bin_hist(const float* __restrict__ refp, int* __restrict__ hist, int N) {
    const int n = blockIdx.x * blockDim.x + threadIdx.x;
    if (n < N) atomicAdd(&hist[bin_of(refp[2 * n], refp[2 * n + 1])], 1);
}

__global__ __launch_bounds__(256)
void bin_scan(const int* __restrict__ hist, int* __restrict__ binptr) {
    __shared__ int part[256];
    const int t = threadIdx.x;
    int vals[16], excl[16], run = 0;
#pragma unroll
    for (int i = 0; i < 16; ++i) { vals[i] = hist[t * 16 + i]; }
#pragma unroll
    for (int i = 0; i < 16; ++i) { excl[i] = run; run += vals[i]; }
    part[t] = run;
    __syncthreads();
    int off = 0;
    for (int i = 0; i < t; ++i) off += part[i];
#pragma unroll
    for (int i = 0; i < 16; ++i) binptr[t * 16 + i] = off + excl[i];
}

__global__ void bin_scatter(const float* __restrict__ refp, int* __restrict__ binptr,
                            int* __restrict__ perm, int N) {
    const int n = blockIdx.x * blockDim.x + threadIdx.x;
    if (n < N) {
        const int b = bin_of(refp[2 * n], refp[2 * n + 1]);
        const int pos = atomicAdd(&binptr[b], 1);
        perm[pos] = n;
    }
}

// ---- W_val transpose+cast prep: wvT[n][k] = (f16)W_val[k][n] --------------
__global__ __launch_bounds__(256)
void prep_wvT(const float* __restrict__ W, f16* __restrict__ wvT) {
    const int k = blockIdx.x, n = threadIdx.x;
    wvT[(size_t)n * 256 + k] = (f16)W[(size_t)k * 256 + n];
}

// ---- MFMA f16 projection: VP[px][256] = (f16)(V[px][:] @ W_val + b_val) ---
// Block: 64 pixels, 4 waves; wave w owns output channels [w*64, w*64+64).
// mfma roles: A-op = W-frags (D rows = channels), B-op = v-frags (D cols =
// pixels). Both operands use the same per-lane K mapping (kg*8+j), so any
// internal K permutation cancels. C/D: col=lane&15 (pixel), row=kg*4+reg
// (channel) [guide §3, m89-verified].
__global__ __launch_bounds__(256)
void proj_val(const float* __restrict__ V, const f16* __restrict__ wvT,
              const float* __restrict__ bval, f16* __restrict__ VP) {
    __shared__ f16 At[64][264];   // v-tile f16, padded stride (528 B)
    const int tid = threadIdx.x;
    const long px0 = (long)blockIdx.x * 64;

    // stage V tile -> f16 LDS. Lane-contiguous global reads (1KB runs),
    // conflict-free contiguous LDS writes.
    {
        const int wv_ = tid >> 6, ln_ = tid & 63;
#pragma unroll
        for (int i = 0; i < 16; ++i) {
            const int px = wv_ + i * 4;
            const float4 v4 = *(const float4*)(V + (px0 + px) * 256 + ln_ * 4);
            f16x4 h4 = {(f16)v4.x, (f16)v4.y, (f16)v4.z, (f16)v4.w};
            *(f16x4*)(&At[px][ln_ * 4]) = h4;
        }
    }
    __syncthreads();

    const int wave = tid >> 6, lane = tid & 63;
    const int ch0 = wave * 64;
    const int l15 = lane & 15, kg = lane >> 4;

    f32x4 acc[4][4];   // [pxtile][chtile]
#pragma unroll
    for (int a = 0; a < 4; ++a)
#pragma unroll
        for (int b = 0; b < 4; ++b) acc[a][b] = (f32x4){0.f, 0.f, 0.f, 0.f};

#pragma unroll
    for (int ks = 0; ks < 8; ++ks) {
        f16x8 wf[4];
#pragma unroll
        for (int ct = 0; ct < 4; ++ct)
            wf[ct] = *(const f16x8*)(wvT + (size_t)(ch0 + ct * 16 + l15) * 256 + ks * 32 + kg * 8);
        f16x8 vf[4];
#pragma unroll
        for (int pt = 0; pt < 4; ++pt)
            vf[pt] = *(const f16x8*)(&At[pt * 16 + l15][ks * 32 + kg * 8]);
#pragma unroll
        for (int pt = 0; pt < 4; ++pt)
#pragma unroll
            for (int ct = 0; ct < 4; ++ct)
                acc[pt][ct] = __builtin_amdgcn_mfma_f32_16x16x32_f16(wf[ct], vf[pt], acc[pt][ct], 0, 0, 0);
    }

    // epilogue: D[ch][px]; lane holds px=l15, ch=kg*4+reg (4 consecutive) ->
    // packed f16x4 (8B) stores into row-major VP[px][ch].
#pragma unroll
    for (int ct = 0; ct < 4; ++ct) {
        const int chb = ch0 + ct * 16 + kg * 4;
        const float4 bv = *(const float4*)(bval + chb);
#pragma unroll
        for (int pt = 0; pt < 4; ++pt) {
            f16x4 o = {(f16)(acc[pt][ct].x + bv.x), (f16)(acc[pt][ct].y + bv.y),
                       (f16)(acc[pt][ct].z + bv.z), (f16)(acc[pt][ct].w + bv.w)};
            *(f16x4*)(VP + (px0 + pt * 16 + l15) * 256 + chb) = o;
        }
    }
}

// ---- gather from vp: 8 queries/block; thread (q=tid>>5, h=(tid>>2)&7,
// s=tid&3) owns channels h*32+s*8..+8. 64B/corner total across 4 s-lanes.
#define GQPB 8
__global__
void gather_vp(const float* __restrict__ offs_all,
               const float* __restrict__ logits_all,
               const float* __restrict__ refpts,
               const int* __restrict__ qoff, int n_off,
               const int* __restrict__ perm,
               const f16* __restrict__ vp0, const f16* __restrict__ vp1,
               const f16* __restrict__ vp2, const f16* __restrict__ vp3,
               float* __restrict__ val_out) {
    __shared__ float sOff[GQPB][256];
    __shared__ float sAttn[GQPB][128];
    __shared__ int   sQ[GQPB];
    const int tid = threadIdx.x;

    const int bid = blockIdx.x;
    const int cpx = gridDim.x >> 3;
    const int swz = (bid & 7) * cpx + (bid >> 3);
    const int n0p = swz * GQPB;

    if (tid < GQPB) sQ[tid] = perm[n0p + tid];
    __syncthreads();

    {
        const int q = tid >> 5, i = tid & 31;
        const int nq = sQ[q];
        ((f32x4*)sOff[q])[i]      = ((const f32x4*)(offs_all + (size_t)nq * 256))[i];
        ((f32x4*)sOff[q])[i + 32] = ((const f32x4*)(offs_all + (size_t)nq * 256))[i + 32];
        ((f32x4*)sAttn[q])[i]     = ((const f32x4*)(logits_all + (size_t)nq * 128))[i];
    }
    __syncthreads();

    if (tid < GQPB * 8) {
        float* row = &sAttn[tid >> 3][(tid & 7) * 16];
        float m = -1e30f;
#pragma unroll
        for (int i = 0; i < 16; ++i) m = fmaxf(m, row[i]);
        float s = 0.f;
#pragma unroll
        for (int i = 0; i < 16; ++i) { const float e = expf(row[i] - m); row[i] = e; s += e; }
        const float inv = 1.f / s;
#pragma unroll
        for (int i = 0; i < 16; ++i) row[i] *= inv;
    }
    __syncthreads();

    const int q = tid >> 5, h = (tid >> 2) & 7, s = tid & 3;
    const int n = sQ[q];
    int b = 0;
    for (int i = 1; i < n_off; ++i) if (n >= qoff[i]) b = i;
    const float ri = refpts[2 * n], rj = refpts[2 * n + 1];
    const int choff = h * 32 + s * 8;

    float acc[8];
#pragma unroll
    for (int j = 0; j < 8; ++j) acc[j] = 0.f;

#pragma unroll
    for (int l = 0; l < 4; ++l) {
        const int hw = (l == 0 ? 64 : (l == 1 ? 128 : (l == 2 ? 256 : 512)));
        const float sc = (float)hw * (1.0f / 512.0f);
        const f16* vbl = (l == 0 ? vp0 : (l == 1 ? vp1 : (l == 2 ? vp2 : vp3)));
        const f16* __restrict__ vb = vbl + (size_t)b * ((size_t)hw * hw * 256) + choff;

#pragma unroll
        for (int pp = 0; pp < 4; pp += 2) {
            int   o[8];
            float wgt[8];
#pragma unroll
            for (int pq = 0; pq < 2; ++pq) {
                const int p = pp + pq;
                const int oi = ((h * 4 + l) * 4 + p) * 2;
                const float fi = (ri + sOff[q][oi]) * sc;
                const float fj = (rj + sOff[q][oi + 1]) * sc;
                const float a = sAttn[q][(h * 4 + l) * 4 + p];
                const float sci = fmaxf(fi - 0.5f, 0.f);
                const float scj = fmaxf(fj - 0.5f, 0.f);
                const float fl_i = floorf(sci), fl_j = floorf(scj);
                const int i0 = (int)fl_i, j0 = (int)fl_j;
                const float fri = sci - fl_i, frj = scj - fl_j;
                const int i0c = min(i0, hw - 1), i1c = min(i0 + 1, hw - 1);
                const int j0c = min(j0, hw - 1), j1c = min(j0 + 1, hw - 1);
                const float uw = 1.f - fri, lw = 1.f - frj;
                o[pq * 4 + 0] = (i0c * hw + j0c) << 8;
                o[pq * 4 + 1] = (i0c * hw + j1c) << 8;
                o[pq * 4 + 2] = (i1c * hw + j0c) << 8;
                o[pq * 4 + 3] = (i1c * hw + j1c) << 8;
                wgt[pq * 4 + 0] = uw * lw * a;
                wgt[pq * 4 + 1] = uw * frj * a;
                wgt[pq * 4 + 2] = fri * lw * a;
                wgt[pq * 4 + 3] = fri * frj * a;
            }

            f16x8 buf[8];
#pragma unroll
            for (int k = 0; k < 8; ++k)
                buf[k] = *(const f16x8*)(vb + (size_t)o[k]);
            asm volatile("" : "+v"(buf[0]), "+v"(buf[1]), "+v"(buf[2]), "+v"(buf[3]),
                              "+v"(buf[4]), "+v"(buf[5]), "+v"(buf[6]), "+v"(buf[7])
                            :: "memory");
#pragma unroll
            for (int k = 0; k < 8; ++k) {
                const float wv = wgt[k];
#pragma unroll
                for (int j = 0; j < 8; ++j)
                    acc[j] = fmaf(wv, (float)buf[k][j], acc[j]);
            }
        }
    }

    float* op = val_out + (size_t)n * 256 + choff;
    *(f32x4*)op       = (f32x4){acc[0], acc[1], acc[2], acc[3]};
    *(f32x4*)(op + 4) = (f32x4){acc[4], acc[5], acc[6], acc[7]};
}

// ---------------- round-10 fallback sampler (raw f32 gather) ----------------
#define QPB 2
__global__
void sample_agg_proj(const float* __restrict__ offs_all,
                     const float* __restrict__ logits_all,
                     const float* __restrict__ refpts,
                     const int* __restrict__ qoff, int n_off,
                     const int* __restrict__ perm,
                     const float* __restrict__ v0, const float* __restrict__ v1,
                     const float* __restrict__ v2, const float* __restrict__ v3,
                     const float* __restrict__ W_val, const float* __restrict__ b_val,
                     float* __restrict__ val_out) {
    __shared__ float sOff[QPB][256];
    __shared__ float sAttn[QPB][128];
    __shared__ int   sQ[QPB];
    __shared__ float sAgg[QPB][8][256];
    const int tid = threadIdx.x;

    const int bid = blockIdx.x;
    const int cpx = gridDim.x >> 3;
    const int swz = (bid & 7) * cpx + (bid >> 3);
    const int n0p = swz * QPB;

    if (tid < QPB) sQ[tid] = perm[n0p + tid];
    __syncthreads();
    const int nA = sQ[0], nB = sQ[1];

    if (tid < 64)       ((f32x4*)sOff[0])[tid]        = ((const f32x4*)(offs_all   + (size_t)nA * 256))[tid];
    else if (tid < 128) ((f32x4*)sOff[1])[tid - 64]   = ((const f32x4*)(offs_all   + (size_t)nB * 256))[tid - 64];
    else if (tid < 160) ((f32x4*)sAttn[0])[tid - 128] = ((const f32x4*)(logits_all + (size_t)nA * 128))[tid - 128];
    else if (tid < 192) ((f32x4*)sAttn[1])[tid - 160] = ((const f32x4*)(logits_all + (size_t)nB * 128))[tid - 160];
    __syncthreads();

    if (tid < QPB * 8) {
        float* row = &sAttn[tid >> 3][(tid & 7) * 16];
        float m = -1e30f;
#pragma unroll
        for (int i = 0; i < 16; ++i) m = fmaxf(m, row[i]);
        float s = 0.f;
#pragma unroll
        for (int i = 0; i < 16; ++i) { const float e = expf(row[i] - m); row[i] = e; s += e; }
        const float inv = 1.f / s;
#pragma unroll
        for (int i = 0; i < 16; ++i) row[i] *= inv;
    }
    __syncthreads();

    const int wave = tid >> 6, lane = tid & 63;
    const int h0 = wave << 1;

    int b0 = 0, b1 = 0;
    for (int i = 1; i < n_off; ++i) {
        if (nA >= qoff[i]) b0 = i;
        if (nB >= qoff[i]) b1 = i;
    }
    const float riA = refpts[2 * nA], rjA = refpts[2 * nA + 1];
    const float riB = refpts[2 * nB], rjB = refpts[2 * nB + 1];

    for (int q = 0; q < QPB; ++q) {
        const int b = (q == 0 ? b0 : b1);
        const float ri = (q == 0 ? riA : riB);
        const float rj = (q == 0 ? rjA : rjB);

        f32x4 accA = (f32x4){0.f, 0.f, 0.f, 0.f};
        f32x4 accB = (f32x4){0.f, 0.f, 0.f, 0.f};

#pragma unroll
        for (int l = 0; l < 4; ++l) {
            const int hw = (l == 0 ? 64 : (l == 1 ? 128 : (l == 2 ? 256 : 512)));
            const float sc = (float)hw * (1.0f / 512.0f);
            const float* vbl = (l == 0 ? v0 : (l == 1 ? v1 : (l == 2 ? v2 : v3)));
            const float* __restrict__ vb = vbl + (size_t)b * ((size_t)hw * hw * 256);

#pragma unroll
            for (int p = 0; p < 4; ++p) {
                int   o[8];
                float wgt[8];
#pragma unroll
                for (int hh = 0; hh < 2; ++hh) {
                    const int h_ = h0 + hh;
                    const int oi = ((h_ * 4 + l) * 4 + p) * 2;
                    const float fi = (ri + sOff[q][oi]) * sc;
                    const float fj = (rj + sOff[q][oi + 1]) * sc;
                    const float a = sAttn[q][(h_ * 4 + l) * 4 + p];
                    const float sci = fmaxf(fi - 0.5f, 0.f);
                    const float scj = fmaxf(fj - 0.5f, 0.f);
                    const float fl_i = floorf(sci), fl_j = floorf(scj);
                    const int i0 = (int)fl_i, j0 = (int)fl_j;
                    const float fri = sci - fl_i, frj = scj - fl_j;
                    const int i0c = min(i0, hw - 1), i1c = min(i0 + 1, hw - 1);
                    const int j0c = min(j0, hw - 1), j1c = min(j0 + 1, hw - 1);
                    const float uw = 1.f - fri, lw = 1.f - frj;
                    o[hh * 4 + 0] = (i0c * hw + j0c) << 8;
                    o[hh * 4 + 1] = (i0c * hw + j1c) << 8;
                    o[hh * 4 + 2] = (i1c * hw + j0c) << 8;
                    o[hh * 4 + 3] = (i1c * hw + j1c) << 8;
                    wgt[hh * 4 + 0] = uw * lw * a;
                    wgt[hh * 4 + 1] = uw * frj * a;
                    wgt[hh * 4 + 2] = fri * lw * a;
                    wgt[hh * 4 + 3] = fri * frj * a;
                }

                f32x4 buf[8];
#pragma unroll
                for (int k = 0; k < 8; ++k)
                    buf[k] = ((const f32x4*)(vb + o[k]))[lane];
                asm volatile("" : "+v"(buf[0]), "+v"(buf[1]), "+v"(buf[2]), "+v"(buf[3]),
                                  "+v"(buf[4]), "+v"(buf[5]), "+v"(buf[6]), "+v"(buf[7])
                                :: "memory");
#pragma unroll
                for (int k = 0; k < 8; ++k) {
                    const float wv = wgt[k];
                    if (k < 4) {
                        accA[0] = fmaf(wv, buf[k][0], accA[0]);
                        accA[1] = fmaf(wv, buf[k][1], accA[1]);
                        accA[2] = fmaf(wv, buf[k][2], accA[2]);
                        accA[3] = fmaf(wv, buf[k][3], accA[3]);
                    } else {
                        accB[0] = fmaf(wv, buf[k][0], accB[0]);
                        accB[1] = fmaf(wv, buf[k][1], accB[1]);
                        accB[2] = fmaf(wv, buf[k][2], accB[2]);
                        accB[3] = fmaf(wv, buf[k][3], accB[3]);
                    }
                }
            }
        }

        ((f32x4*)sAgg[q][h0 + 0])[lane] = accA;
        ((f32x4*)sAgg[q][h0 + 1])[lane] = accB;
    }
    __syncthreads();

    const int c2 = tid, h2 = tid >> 5;
    float s[QPB];
#pragma unroll
    for (int q = 0; q < QPB; ++q) s[q] = b_val[c2];
    for (int k4 = 0; k4 < 64; ++k4) {
        const float w0 = W_val[(k4 * 4 + 0) * 256 + c2];
        const float w1 = W_val[(k4 * 4 + 1) * 256 + c2];
        const float w2 = W_val[(k4 * 4 + 2) * 256 + c2];
        const float w3 = W_val[(k4 * 4 + 3) * 256 + c2];
#pragma unroll
        for (int q = 0; q < QPB; ++q) {
            const f32x4 av = ((const f32x4*)sAgg[q][h2])[k4];
            float t = s[q];
            t = fmaf(av.x, w0, t);
            t = fmaf(av.y, w1, t);
            t = fmaf(av.z, w2, t);
            t = fmaf(av.w, w3, t);
            s[q] = t;
        }
    }
    val_out[(size_t)nA * 256 + c2] = s[0];
    val_out[(size_t)nB * 256 + c2] = s[1];
}

extern "C" void kernel_launch(void* const* d_in, const int* in_sizes, int n_in,
                              void* d_out, int out_size, void* d_ws, size_t ws_size,
                              hipStream_t stream) {
    const float* query  = (const float*)d_in[0];
    const int*   qoff   = (const int*)d_in[1];
    const float* refp   = (const float*)d_in[2];
    const float* v0     = (const float*)d_in[3];
    const float* v1     = (const float*)d_in[4];
    const float* v2     = (const float*)d_in[5];
    const float* v3     = (const float*)d_in[6];
    const float* W_off  = (const float*)d_in[7];
    const float* b_off  = (const float*)d_in[8];
    const float* W_attn = (const float*)d_in[9];
    const float* b_attn = (const float*)d_in[10];
    const float* W_val  = (const float*)d_in[11];
    const float* b_val  = (const float*)d_in[12];
    const float* W_out  = (const float*)d_in[13];
    const float* b_out  = (const float*)d_in[14];
    float* out = (float*)d_out;

    const int N = in_sizes[0] / 256;   // 16384
    const int n_off = in_sizes[1];     // 2

    float* P1off  = (float*)d_ws;                     // N*256 f32
    float* P1attn = P1off + (size_t)N * 256;          // N*128 f32
    int*   hist   = (int*)(P1attn + (size_t)N * 128); // NBINS
    int*   binptr = hist + NBINS;                     // NBINS
    int*   perm   = binptr + NBINS;                   // N

    const int M0 = 2 * 64 * 64, M1 = 2 * 128 * 128, M2 = 2 * 256 * 256, M3 = 2 * 512 * 512;
    const size_t base_b = (size_t)N * 256 * 4 + (size_t)N * 128 * 4 + (size_t)(2 * NBINS + N) * 4;
    const size_t wvT_b = 65536 * sizeof(f16);
    const size_t vp_b = ((size_t)M0 + M1 + M2 + M3) * 256 * sizeof(f16);
    const bool big = ws_size >= base_b + wvT_b + vp_b + 1024;

    hipMemsetAsync(hist, 0, NBINS * sizeof(int), stream);
    bin_hist<<<(N + 255) / 256, 256, 0, stream>>>(refp, hist, N);
    bin_scan<<<1, 256, 0, stream>>>(hist, binptr);
    bin_scatter<<<(N + 255) / 256, 256, 0, stream>>>(refp, binptr, perm, N);

    gemm_rb<256><<<N / 32, 256, 0, stream>>>(query, W_off, b_off, P1off);
    gemm_rb<128><<<N / 32, 128, 0, stream>>>(query, W_attn, b_attn, P1attn);

    if (big) {
        f16* wvT = (f16*)((char*)d_ws + base_b);
        f16* vp0 = wvT + 65536;
        f16* vp1 = vp0 + (size_t)M0 * 256;
        f16* vp2 = vp1 + (size_t)M1 * 256;
        f16* vp3 = vp2 + (size_t)M2 * 256;

        prep_wvT<<<256, 256, 0, stream>>>(W_val, wvT);
        proj_val<<<M0 / 64, 256, 0, stream>>>(v0, wvT, b_val, vp0);
        proj_val<<<M1 / 64, 256, 0, stream>>>(v1, wvT, b_val, vp1);
        proj_val<<<M2 / 64, 256, 0, stream>>>(v2, wvT, b_val, vp2);
        proj_val<<<M3 / 64, 256, 0, stream>>>(v3, wvT, b_val, vp3);

        gather_vp<<<N / GQPB, 256, 0, stream>>>(P1off, P1attn, refp, qoff, n_off,
                                                perm, vp0, vp1, vp2, vp3, out);
    } else {
        sample_agg_proj<<<N / QPB, 256, 0, stream>>>(P1off, P1attn, refp, qoff, n_off,
                                                     perm, v0, v1, v2, v3, W_val, b_val, out);
    }

    gemm_rb<256><<<N / 32, 256, 0, stream>>>(out, W_out, b_out, out);
}

// Round 12
// 635.490 us; speedup vs baseline: 2.2134x; 2.2134x over previous
//
#include <hip/hip_runtime.h>

// ---------------------------------------------------------------------------
// Sparse MS-Deformable Attention, f32 (+f16 projected value maps).
// Round 12: fix round-11's two execution pathologies.
//  (a) gather_vp was spill-bound (WRITE 1.65 GB scratch): no launch_bounds
//      => hipcc assumes 1024-thread workgroup => VGPR cap 64 => buf[8] f16x8
//      spilled. __launch_bounds__(256) raises the cap to 256 (no min-waves
//      contract, which is what caused rounds 4/6/7 spills).
//  (b) proj_val weight loads were 64 scattered 16B runs per instruction
//      (2.8 GB of bad-shape L2 traffic). W_val is now pre-swizzled into
//      MFMA-fragment order so each weight load is one contiguous 1KB
//      wave instruction. Identical per-lane values -> math unchanged.
// ---------------------------------------------------------------------------

typedef float f32x4 __attribute__((ext_vector_type(4)));
typedef _Float16 f16;
typedef f16 f16x8 __attribute__((ext_vector_type(8)));
typedef f16 f16x4 __attribute__((ext_vector_type(4)));

// Y[n, 0:M] = X[n, 0:256] @ W[256, M] + bias ; 32 rows/block, M threads,
// thread tile = 8 queries x 4 cols. Safe in-place (Y==X).
template<int M>
__global__ __launch_bounds__(M)
void gemm_rb(const float* __restrict__ X, const float* __restrict__ W,
             const float* __restrict__ bias, float* __restrict__ Y) {
    __shared__ float xt[32 * 256];
    const int tid = threadIdx.x;
    const long row0 = (long)blockIdx.x * 32;
    const float4* src = (const float4*)(X + row0 * 256);
    float4* dst4 = (float4*)xt;
    for (int i = tid; i < 32 * 64; i += M) dst4[i] = src[i];
    __syncthreads();

    constexpr int CG = M / 4;
    const int cg = tid % CG, qg = tid / CG;
    const int c0 = cg * 4, q0 = qg * 8;

    f32x4 acc[8];
#pragma unroll
    for (int qi = 0; qi < 8; ++qi) acc[qi] = (f32x4){0.f, 0.f, 0.f, 0.f};

    for (int k4 = 0; k4 < 64; ++k4) {
        f32x4 w[4];
#pragma unroll
        for (int r = 0; r < 4; ++r)
            w[r] = *(const f32x4*)&W[(size_t)(k4 * 4 + r) * M + c0];
        f32x4 xv[8];
#pragma unroll
        for (int qi = 0; qi < 8; ++qi)
            xv[qi] = *(const f32x4*)&xt[(q0 + qi) * 256 + k4 * 4];
#pragma unroll
        for (int qi = 0; qi < 8; ++qi) {
            f32x4 a = acc[qi];
            const f32x4 x = xv[qi];
            a.x = fmaf(x.x, w[0].x, a.x); a.y = fmaf(x.x, w[0].y, a.y);
            a.z = fmaf(x.x, w[0].z, a.z); a.w = fmaf(x.x, w[0].w, a.w);
            a.x = fmaf(x.y, w[1].x, a.x); a.y = fmaf(x.y, w[1].y, a.y);
            a.z = fmaf(x.y, w[1].z, a.z); a.w = fmaf(x.y, w[1].w, a.w);
            a.x = fmaf(x.z, w[2].x, a.x); a.y = fmaf(x.z, w[2].y, a.y);
            a.z = fmaf(x.z, w[2].z, a.z); a.w = fmaf(x.z, w[2].w, a.w);
            a.x = fmaf(x.w, w[3].x, a.x); a.y = fmaf(x.w, w[3].y, a.y);
            a.z = fmaf(x.w, w[3].z, a.z); a.w = fmaf(x.w, w[3].w, a.w);
            acc[qi] = a;
        }
    }

    const f32x4 bv = *(const f32x4*)&bias[c0];
#pragma unroll
    for (int qi = 0; qi < 8; ++qi) {
        f32x4 o = acc[qi];
        o.x += bv.x; o.y += bv.y; o.z += bv.z; o.w += bv.w;
        *(f32x4*)&Y[(size_t)(row0 + q0 + qi) * M + c0] = o;
    }
}

// ---- spatial binning: 64x64 bins of 8x8 px over the 512x512 base frame ----
#define NBINS 4096

__device__ __forceinline__ int bin_of(float ri, float rj) {
    int bi = (int)ri >> 3, bj = (int)rj >> 3;
    bi = min(63, max(0, bi)); bj = min(63, max(0, bj));
    return bi * 64 + bj;
}

__global__ void bin_hist(const float* __restrict__ refp, int* __restrict__ hist, int N) {
    const int n = blockIdx.x * blockDim.x + threadIdx.x;
    if (n < N) atomicAdd(&hist[bin_of(refp[2 * n], refp[2 * n + 1])], 1);
}

__global__ __launch_bounds__(256)
void bin_scan(const int* __restrict__ hist, int* __restrict__ binptr) {
    __shared__ int part[256];
    const int t = threadIdx.x;
    int vals[16], excl[16], run = 0;
#pragma unroll
    for (int i = 0; i < 16; ++i) { vals[i] = hist[t * 16 + i]; }
#pragma unroll
    for (int i = 0; i < 16; ++i) { excl[i] = run; run += vals[i]; }
    part[t] = run;
    __syncthreads();
    int off = 0;
    for (int i = 0; i < t; ++i) off += part[i];
#pragma unroll
    for (int i = 0; i < 16; ++i) binptr[t * 16 + i] = off + excl[i];
}

__global__ void bin_scatter(const float* __restrict__ refp, int* __restrict__ binptr,
                            int* __restrict__ perm, int N) {
    const int n = blockIdx.x * blockDim.x + threadIdx.x;
    if (n < N) {
        const int b = bin_of(refp[2 * n], refp[2 * n + 1]);
        const int pos = atomicAdd(&binptr[b], 1);
        perm[pos] = n;
    }
}

// ---- W_val swizzle into MFMA-fragment order --------------------------------
// wvF element index: (ks*16 + tile)*512 + lane*8 + j  where lane=(kg<<4)|l15,
// value = (f16)W_val[(ks*32+kg*8+j)*256 + tile*16+l15]. A wave's (ks,ct)
// A-fragment load is then one contiguous 1KB instruction.
__global__ __launch_bounds__(256)
void prep_wvF(const float* __restrict__ W, f16* __restrict__ wvF) {
    const int k = blockIdx.x, n = threadIdx.x;
    const int ks = k >> 5, kg = (k >> 3) & 3, j = k & 7;
    const int tile = n >> 4, l15 = n & 15;
    const int lane = (kg << 4) | l15;
    wvF[((size_t)(ks * 16 + tile) * 512) + lane * 8 + j] = (f16)W[(size_t)k * 256 + n];
}

// ---- MFMA f16 projection: VP[px][256] = (f16)(V[px][:] @ W_val + b_val) ---
// Block: 64 pixels, 4 waves; wave w owns output channels [w*64, w*64+64).
// A-op = weight frags (D rows = channels), B-op = v frags (D cols = pixels).
// C/D: col=lane&15 (pixel), row=kg*4+reg (channel). Verified passing in r11.
__global__ __launch_bounds__(256)
void proj_val(const float* __restrict__ V, const f16* __restrict__ wvF,
              const float* __restrict__ bval, f16* __restrict__ VP) {
    __shared__ f16 At[64][264];   // v-tile f16, padded stride (528 B)
    const int tid = threadIdx.x;
    const long px0 = (long)blockIdx.x * 64;

    {
        const int wv_ = tid >> 6, ln_ = tid & 63;
#pragma unroll
        for (int i = 0; i < 16; ++i) {
            const int px = wv_ + i * 4;
            const float4 v4 = *(const float4*)(V + (px0 + px) * 256 + ln_ * 4);
            f16x4 h4 = {(f16)v4.x, (f16)v4.y, (f16)v4.z, (f16)v4.w};
            *(f16x4*)(&At[px][ln_ * 4]) = h4;
        }
    }
    __syncthreads();

    const int wave = tid >> 6, lane = tid & 63;
    const int l15 = lane & 15, kg = lane >> 4;

    f32x4 acc[4][4];   // [pxtile][chtile]
#pragma unroll
    for (int a = 0; a < 4; ++a)
#pragma unroll
        for (int b = 0; b < 4; ++b) acc[a][b] = (f32x4){0.f, 0.f, 0.f, 0.f};

#pragma unroll
    for (int ks = 0; ks < 8; ++ks) {
        f16x8 wf[4];
#pragma unroll
        for (int ct = 0; ct < 4; ++ct)   // contiguous 1KB per instruction
            wf[ct] = *(const f16x8*)(wvF + ((size_t)(ks * 16 + wave * 4 + ct) * 512) + lane * 8);
        f16x8 vf[4];
#pragma unroll
        for (int pt = 0; pt < 4; ++pt)
            vf[pt] = *(const f16x8*)(&At[pt * 16 + l15][ks * 32 + kg * 8]);
#pragma unroll
        for (int pt = 0; pt < 4; ++pt)
#pragma unroll
            for (int ct = 0; ct < 4; ++ct)
                acc[pt][ct] = __builtin_amdgcn_mfma_f32_16x16x32_f16(wf[ct], vf[pt], acc[pt][ct], 0, 0, 0);
    }

    const int ch0 = wave * 64;
#pragma unroll
    for (int ct = 0; ct < 4; ++ct) {
        const int chb = ch0 + ct * 16 + kg * 4;
        const float4 bv = *(const float4*)(bval + chb);
#pragma unroll
        for (int pt = 0; pt < 4; ++pt) {
            f16x4 o = {(f16)(acc[pt][ct].x + bv.x), (f16)(acc[pt][ct].y + bv.y),
                       (f16)(acc[pt][ct].z + bv.z), (f16)(acc[pt][ct].w + bv.w)};
            *(f16x4*)(VP + (px0 + pt * 16 + l15) * 256 + chb) = o;
        }
    }
}

// ---- gather from vp: 8 queries/block; thread (q=tid>>5, h=(tid>>2)&7,
// s=tid&3) owns channels h*32+s*8..+8. 64B/corner across 4 s-lanes.
#define GQPB 8
__global__ __launch_bounds__(256)
void gather_vp(const float* __restrict__ offs_all,
               const float* __restrict__ logits_all,
               const float* __restrict__ refpts,
               const int* __restrict__ qoff, int n_off,
               const int* __restrict__ perm,
               const f16* __restrict__ vp0, const f16* __restrict__ vp1,
               const f16* __restrict__ vp2, const f16* __restrict__ vp3,
               float* __restrict__ val_out) {
    __shared__ float sOff[GQPB][256];
    __shared__ float sAttn[GQPB][128];
    __shared__ int   sQ[GQPB];
    const int tid = threadIdx.x;

    const int bid = blockIdx.x;
    const int cpx = gridDim.x >> 3;
    const int swz = (bid & 7) * cpx + (bid >> 3);
    const int n0p = swz * GQPB;

    if (tid < GQPB) sQ[tid] = perm[n0p + tid];
    __syncthreads();

    {
        const int q = tid >> 5, i = tid & 31;
        const int nq = sQ[q];
        ((f32x4*)sOff[q])[i]      = ((const f32x4*)(offs_all + (size_t)nq * 256))[i];
        ((f32x4*)sOff[q])[i + 32] = ((const f32x4*)(offs_all + (size_t)nq * 256))[i + 32];
        ((f32x4*)sAttn[q])[i]     = ((const f32x4*)(logits_all + (size_t)nq * 128))[i];
    }
    __syncthreads();

    if (tid < GQPB * 8) {
        float* row = &sAttn[tid >> 3][(tid & 7) * 16];
        float m = -1e30f;
#pragma unroll
        for (int i = 0; i < 16; ++i) m = fmaxf(m, row[i]);
        float s = 0.f;
#pragma unroll
        for (int i = 0; i < 16; ++i) { const float e = expf(row[i] - m); row[i] = e; s += e; }
        const float inv = 1.f / s;
#pragma unroll
        for (int i = 0; i < 16; ++i) row[i] *= inv;
    }
    __syncthreads();

    const int q = tid >> 5, h = (tid >> 2) & 7, s = tid & 3;
    const int n = sQ[q];
    int b = 0;
    for (int i = 1; i < n_off; ++i) if (n >= qoff[i]) b = i;
    const float ri = refpts[2 * n], rj = refpts[2 * n + 1];
    const int choff = h * 32 + s * 8;

    float acc[8];
#pragma unroll
    for (int j = 0; j < 8; ++j) acc[j] = 0.f;

#pragma unroll
    for (int l = 0; l < 4; ++l) {
        const int hw = (l == 0 ? 64 : (l == 1 ? 128 : (l == 2 ? 256 : 512)));
        const float sc = (float)hw * (1.0f / 512.0f);
        const f16* vbl = (l == 0 ? vp0 : (l == 1 ? vp1 : (l == 2 ? vp2 : vp3)));
        const f16* __restrict__ vb = vbl + (size_t)b * ((size_t)hw * hw * 256) + choff;

#pragma unroll
        for (int pp = 0; pp < 4; pp += 2) {
            int   o[8];
            float wgt[8];
#pragma unroll
            for (int pq = 0; pq < 2; ++pq) {
                const int p = pp + pq;
                const int oi = ((h * 4 + l) * 4 + p) * 2;
                const float fi = (ri + sOff[q][oi]) * sc;
                const float fj = (rj + sOff[q][oi + 1]) * sc;
                const float a = sAttn[q][(h * 4 + l) * 4 + p];
                const float sci = fmaxf(fi - 0.5f, 0.f);
                const float scj = fmaxf(fj - 0.5f, 0.f);
                const float fl_i = floorf(sci), fl_j = floorf(scj);
                const int i0 = (int)fl_i, j0 = (int)fl_j;
                const float fri = sci - fl_i, frj = scj - fl_j;
                const int i0c = min(i0, hw - 1), i1c = min(i0 + 1, hw - 1);
                const int j0c = min(j0, hw - 1), j1c = min(j0 + 1, hw - 1);
                const float uw = 1.f - fri, lw = 1.f - frj;
                o[pq * 4 + 0] = (i0c * hw + j0c) << 8;
                o[pq * 4 + 1] = (i0c * hw + j1c) << 8;
                o[pq * 4 + 2] = (i1c * hw + j0c) << 8;
                o[pq * 4 + 3] = (i1c * hw + j1c) << 8;
                wgt[pq * 4 + 0] = uw * lw * a;
                wgt[pq * 4 + 1] = uw * frj * a;
                wgt[pq * 4 + 2] = fri * lw * a;
                wgt[pq * 4 + 3] = fri * frj * a;
            }

            f16x8 buf[8];
#pragma unroll
            for (int k = 0; k < 8; ++k)
                buf[k] = *(const f16x8*)(vb + (size_t)o[k]);
            asm volatile("" : "+v"(buf[0]), "+v"(buf[1]), "+v"(buf[2]), "+v"(buf[3]),
                              "+v"(buf[4]), "+v"(buf[5]), "+v"(buf[6]), "+v"(buf[7])
                            :: "memory");
#pragma unroll
            for (int k = 0; k < 8; ++k) {
                const float wv = wgt[k];
#pragma unroll
                for (int j = 0; j < 8; ++j)
                    acc[j] = fmaf(wv, (float)buf[k][j], acc[j]);
            }
        }
    }

    float* op = val_out + (size_t)n * 256 + choff;
    *(f32x4*)op       = (f32x4){acc[0], acc[1], acc[2], acc[3]};
    *(f32x4*)(op + 4) = (f32x4){acc[4], acc[5], acc[6], acc[7]};
}

// ---------------- round-10 fallback sampler (raw f32 gather) ----------------
#define QPB 2
__global__
void sample_agg_proj(const float* __restrict__ offs_all,
                     const float* __restrict__ logits_all,
                     const float* __restrict__ refpts,
                     const int* __restrict__ qoff, int n_off,
                     const int* __restrict__ perm,
                     const float* __restrict__ v0, const float* __restrict__ v1,
                     const float* __restrict__ v2, const float* __restrict__ v3,
                     const float* __restrict__ W_val, const float* __restrict__ b_val,
                     float* __restrict__ val_out) {
    __shared__ float sOff[QPB][256];
    __shared__ float sAttn[QPB][128];
    __shared__ int   sQ[QPB];
    __shared__ float sAgg[QPB][8][256];
    const int tid = threadIdx.x;

    const int bid = blockIdx.x;
    const int cpx = gridDim.x >> 3;
    const int swz = (bid & 7) * cpx + (bid >> 3);
    const int n0p = swz * QPB;

    if (tid < QPB) sQ[tid] = perm[n0p + tid];
    __syncthreads();
    const int nA = sQ[0], nB = sQ[1];

    if (tid < 64)       ((f32x4*)sOff[0])[tid]        = ((const f32x4*)(offs_all   + (size_t)nA * 256))[tid];
    else if (tid < 128) ((f32x4*)sOff[1])[tid - 64]   = ((const f32x4*)(offs_all   + (size_t)nB * 256))[tid - 64];
    else if (tid < 160) ((f32x4*)sAttn[0])[tid - 128] = ((const f32x4*)(logits_all + (size_t)nA * 128))[tid - 128];
    else if (tid < 192) ((f32x4*)sAttn[1])[tid - 160] = ((const f32x4*)(logits_all + (size_t)nB * 128))[tid - 160];
    __syncthreads();

    if (tid < QPB * 8) {
        float* row = &sAttn[tid >> 3][(tid & 7) * 16];
        float m = -1e30f;
#pragma unroll
        for (int i = 0; i < 16; ++i) m = fmaxf(m, row[i]);
        float s = 0.f;
#pragma unroll
        for (int i = 0; i < 16; ++i) { const float e = expf(row[i] - m); row[i] = e; s += e; }
        const float inv = 1.f / s;
#pragma unroll
        for (int i = 0; i < 16; ++i) row[i] *= inv;
    }
    __syncthreads();

    const int wave = tid >> 6, lane = tid & 63;
    const int h0 = wave << 1;

    int b0 = 0, b1 = 0;
    for (int i = 1; i < n_off; ++i) {
        if (nA >= qoff[i]) b0 = i;
        if (nB >= qoff[i]) b1 = i;
    }
    const float riA = refpts[2 * nA], rjA = refpts[2 * nA + 1];
    const float riB = refpts[2 * nB], rjB = refpts[2 * nB + 1];

    for (int q = 0; q < QPB; ++q) {
        const int b = (q == 0 ? b0 : b1);
        const float ri = (q == 0 ? riA : riB);
        const float rj = (q == 0 ? rjA : rjB);

        f32x4 accA = (f32x4){0.f, 0.f, 0.f, 0.f};
        f32x4 accB = (f32x4){0.f, 0.f, 0.f, 0.f};

#pragma unroll
        for (int l = 0; l < 4; ++l) {
            const int hw = (l == 0 ? 64 : (l == 1 ? 128 : (l == 2 ? 256 : 512)));
            const float sc = (float)hw * (1.0f / 512.0f);
            const float* vbl = (l == 0 ? v0 : (l == 1 ? v1 : (l == 2 ? v2 : v3)));
            const float* __restrict__ vb = vbl + (size_t)b * ((size_t)hw * hw * 256);

#pragma unroll
            for (int p = 0; p < 4; ++p) {
                int   o[8];
                float wgt[8];
#pragma unroll
                for (int hh = 0; hh < 2; ++hh) {
                    const int h_ = h0 + hh;
                    const int oi = ((h_ * 4 + l) * 4 + p) * 2;
                    const float fi = (ri + sOff[q][oi]) * sc;
                    const float fj = (rj + sOff[q][oi + 1]) * sc;
                    const float a = sAttn[q][(h_ * 4 + l) * 4 + p];
                    const float sci = fmaxf(fi - 0.5f, 0.f);
                    const float scj = fmaxf(fj - 0.5f, 0.f);
                    const float fl_i = floorf(sci), fl_j = floorf(scj);
                    const int i0 = (int)fl_i, j0 = (int)fl_j;
                    const float fri = sci - fl_i, frj = scj - fl_j;
                    const int i0c = min(i0, hw - 1), i1c = min(i0 + 1, hw - 1);
                    const int j0c = min(j0, hw - 1), j1c = min(j0 + 1, hw - 1);
                    const float uw = 1.f - fri, lw = 1.f - frj;
                    o[hh * 4 + 0] = (i0c * hw + j0c) << 8;
                    o[hh * 4 + 1] = (i0c * hw + j1c) << 8;
                    o[hh * 4 + 2] = (i1c * hw + j0c) << 8;
                    o[hh * 4 + 3] = (i1c * hw + j1c) << 8;
                    wgt[hh * 4 + 0] = uw * lw * a;
                    wgt[hh * 4 + 1] = uw * frj * a;
                    wgt[hh * 4 + 2] = fri * lw * a;
                    wgt[hh * 4 + 3] = fri * frj * a;
                }

                f32x4 buf[8];
#pragma unroll
                for (int k = 0; k < 8; ++k)
                    buf[k] = ((const f32x4*)(vb + o[k]))[lane];
                asm volatile("" : "+v"(buf[0]), "+v"(buf[1]), "+v"(buf[2]), "+v"(buf[3]),
                                  "+v"(buf[4]), "+v"(buf[5]), "+v"(buf[6]), "+v"(buf[7])
                                :: "memory");
#pragma unroll
                for (int k = 0; k < 8; ++k) {
                    const float wv = wgt[k];
                    if (k < 4) {
                        accA[0] = fmaf(wv, buf[k][0], accA[0]);
                        accA[1] = fmaf(wv, buf[k][1], accA[1]);
                        accA[2] = fmaf(wv, buf[k][2], accA[2]);
                        accA[3] = fmaf(wv, buf[k][3], accA[3]);
                    } else {
                        accB[0] = fmaf(wv, buf[k][0], accB[0]);
                        accB[1] = fmaf(wv, buf[k][1], accB[1]);
                        accB[2] = fmaf(wv, buf[k][2], accB[2]);
                        accB[3] = fmaf(wv, buf[k][3], accB[3]);
                    }
                }
            }
        }

        ((f32x4*)sAgg[q][h0 + 0])[lane] = accA;
        ((f32x4*)sAgg[q][h0 + 1])[lane] = accB;
    }
    __syncthreads();

    const int c2 = tid, h2 = tid >> 5;
    float s[QPB];
#pragma unroll
    for (int q = 0; q < QPB; ++q) s[q] = b_val[c2];
    for (int k4 = 0; k4 < 64; ++k4) {
        const float w0 = W_val[(k4 * 4 + 0) * 256 + c2];
        const float w1 = W_val[(k4 * 4 + 1) * 256 + c2];
        const float w2 = W_val[(k4 * 4 + 2) * 256 + c2];
        const float w3 = W_val[(k4 * 4 + 3) * 256 + c2];
#pragma unroll
        for (int q = 0; q < QPB; ++q) {
            const f32x4 av = ((const f32x4*)sAgg[q][h2])[k4];
            float t = s[q];
            t = fmaf(av.x, w0, t);
            t = fmaf(av.y, w1, t);
            t = fmaf(av.z, w2, t);
            t = fmaf(av.w, w3, t);
            s[q] = t;
        }
    }
    val_out[(size_t)nA * 256 + c2] = s[0];
    val_out[(size_t)nB * 256 + c2] = s[1];
}

extern "C" void kernel_launch(void* const* d_in, const int* in_sizes, int n_in,
                              void* d_out, int out_size, void* d_ws, size_t ws_size,
                              hipStream_t stream) {
    const float* query  = (const float*)d_in[0];
    const int*   qoff   = (const int*)d_in[1];
    const float* refp   = (const float*)d_in[2];
    const float* v0     = (const float*)d_in[3];
    const float* v1     = (const float*)d_in[4];
    const float* v2     = (const float*)d_in[5];
    const float* v3     = (const float*)d_in[6];
    const float* W_off  = (const float*)d_in[7];
    const float* b_off  = (const float*)d_in[8];
    const float* W_attn = (const float*)d_in[9];
    const float* b_attn = (const float*)d_in[10];
    const float* W_val  = (const float*)d_in[11];
    const float* b_val  = (const float*)d_in[12];
    const float* W_out  = (const float*)d_in[13];
    const float* b_out  = (const float*)d_in[14];
    float* out = (float*)d_out;

    const int N = in_sizes[0] / 256;   // 16384
    const int n_off = in_sizes[1];     // 2

    float* P1off  = (float*)d_ws;                     // N*256 f32
    float* P1attn = P1off + (size_t)N * 256;          // N*128 f32
    int*   hist   = (int*)(P1attn + (size_t)N * 128); // NBINS
    int*   binptr = hist + NBINS;                     // NBINS
    int*   perm   = binptr + NBINS;                   // N

    const int M0 = 2 * 64 * 64, M1 = 2 * 128 * 128, M2 = 2 * 256 * 256, M3 = 2 * 512 * 512;
    const size_t base_b = (size_t)N * 256 * 4 + (size_t)N * 128 * 4 + (size_t)(2 * NBINS + N) * 4;
    const size_t wvF_b = 65536 * sizeof(f16);
    const size_t vp_b = ((size_t)M0 + M1 + M2 + M3) * 256 * sizeof(f16);
    const bool big = ws_size >= base_b + wvF_b + vp_b + 1024;

    hipMemsetAsync(hist, 0, NBINS * sizeof(int), stream);
    bin_hist<<<(N + 255) / 256, 256, 0, stream>>>(refp, hist, N);
    bin_scan<<<1, 256, 0, stream>>>(hist, binptr);
    bin_scatter<<<(N + 255) / 256, 256, 0, stream>>>(refp, binptr, perm, N);

    gemm_rb<256><<<N / 32, 256, 0, stream>>>(query, W_off, b_off, P1off);
    gemm_rb<128><<<N / 32, 128, 0, stream>>>(query, W_attn, b_attn, P1attn);

    if (big) {
        f16* wvF = (f16*)((char*)d_ws + base_b);
        f16* vp0 = wvF + 65536;
        f16* vp1 = vp0 + (size_t)M0 * 256;
        f16* vp2 = vp1 + (size_t)M1 * 256;
        f16* vp3 = vp2 + (size_t)M2 * 256;

        prep_wvF<<<256, 256, 0, stream>>>(W_val, wvF);
        proj_val<<<M0 / 64, 256, 0, stream>>>(v0, wvF, b_val, vp0);
        proj_val<<<M1 / 64, 256, 0, stream>>>(v1, wvF, b_val, vp1);
        proj_val<<<M2 / 64, 256, 0, stream>>>(v2, wvF, b_val, vp2);
        proj_val<<<M3 / 64, 256, 0, stream>>>(v3, wvF, b_val, vp3);

        gather_vp<<<N / GQPB, 256, 0, stream>>>(P1off, P1attn, refp, qoff, n_off,
                                                perm, vp0, vp1, vp2, vp3, out);
    } else {
        sample_agg_proj<<<N / QPB, 256, 0, stream>>>(P1off, P1attn, refp, qoff, n_off,
                                                     perm, v0, v1, v2, v3, W_val, b_val, out);
    }

    gemm_rb<256><<<N / 32, 256, 0, stream>>>(out, W_out, b_out, out);
}